// Round 1
// baseline (145.850 us; speedup 1.0000x reference)
//
#include <hip/hip_runtime.h>
#include <math.h>

#define N 4096
#define NB 2
#define THRESHOLD_FACTOR 1.25

// ---------------------------------------------------------------------------
// Kernel 1: per-batch mean/std of dist_sq via separable sums (O(n) not O(n^2)).
// dist[s,t] = a_s*A_t + b_s*B_t with a=x^2, b=y^2, A=(1-x)^2, B=(1-y)^2.
// sum d   = Sa*SA + Sb*SB
// sum d^2 = Saa*SAA + Sbb*SBB + 2*Sab*SAB
// One block per batch. LDS tree padded to 11 doubles/row: stride 22 dwords,
// gcd(22,32)=2 -> 2-way bank aliasing (free on CDNA4) instead of 8-way.
// ---------------------------------------------------------------------------
__global__ __launch_bounds__(256) void stats_kernel(const float* __restrict__ r,
                                                    float* __restrict__ thr) {
    int b = blockIdx.x;
    const float2* rb2 = (const float2*)(r + (size_t)b * N * 2);
    int tid = threadIdx.x;

    double s[10];
#pragma unroll
    for (int i = 0; i < 10; ++i) s[i] = 0.0;

    for (int idx = tid; idx < N; idx += 256) {
        float2 p = rb2[idx];
        float x = p.x;
        float y = p.y;
        double a  = (double)x * (double)x;
        double bb = (double)y * (double)y;
        double ax = 1.0 - (double)x;
        double by = 1.0 - (double)y;
        double A  = ax * ax;
        double Bv = by * by;
        s[0] += a;      s[1] += bb;      s[2] += A;      s[3] += Bv;
        s[4] += a * a;  s[5] += bb * bb; s[6] += a * bb;
        s[7] += A * A;  s[8] += Bv * Bv; s[9] += A * Bv;
    }

    // one-pass tree reduction over all 10 quantities (padded row: 11 doubles)
    __shared__ double red[256][11];
#pragma unroll
    for (int q = 0; q < 10; ++q) red[tid][q] = s[q];
    __syncthreads();
    for (int st = 128; st > 0; st >>= 1) {
        if (tid < st) {
#pragma unroll
            for (int q = 0; q < 10; ++q) red[tid][q] += red[tid + st][q];
        }
        __syncthreads();
    }

    if (tid == 0) {
        double t0 = red[0][0], t1 = red[0][1], t2 = red[0][2], t3 = red[0][3];
        double t4 = red[0][4], t5 = red[0][5], t6 = red[0][6];
        double t7 = red[0][7], t8 = red[0][8], t9 = red[0][9];
        double pairs = (double)N * (double)N;
        double sum_d  = t0 * t2 + t1 * t3;
        double sum_d2 = t4 * t7 + t5 * t8 + 2.0 * t6 * t9;
        double mean = sum_d / pairs;
        double var = (sum_d2 - sum_d * sum_d / pairs) / (pairs - 1.0);
        double sd = sqrt(var);
        if (sd < 1e-6) sd = 1e-6;
        thr[b] = (float)(mean + THRESHOLD_FACTOR * sd);
    }
}

// ---------------------------------------------------------------------------
// Kernel 2: one block per PAIR of rows (b, s0) and (b, s0+1). The two rows
// share every t-point load (halves load instructions + L1 traffic vs one
// row/block) and provide two independent ALU streams per load for ILP.
// Each thread computes 16 t-entries per row (4 groups of 4 consecutive t for
// float4 stores), block-reduces both row sums, normalizes, writes coalesced
// float4. All math native: v_exp_f32 (__expf), v_rsq_f32, v_rcp_f32.
// ---------------------------------------------------------------------------
__global__ __launch_bounds__(256) void attn_kernel(const float* __restrict__ r,
                                                   const float* __restrict__ thr,
                                                   float* __restrict__ out) {
    int blk = blockIdx.x;              // 0 .. NB*2048-1
    int b = blk >> 11;                 // 2048 blocks per batch
    int s0 = (blk & 2047) << 1;        // rows s0, s0+1
    const float* rb = r + (size_t)b * N * 2;

    // r[b, s0, :] and r[b, s0+1, :] in one aligned float4
    float4 rs = *(const float4*)(rb + (size_t)s0 * 2);
    float ax = rs.x, ay = rs.y;        // row A = s0
    float bx = rs.z, by = rs.w;        // row B = s0+1
    float threshold = thr[b];

    int tid = threadIdx.x;
    float va[16], vb[16];
    float sumA = 0.0f, sumB = 0.0f;

#pragma unroll
    for (int g = 0; g < 4; ++g) {
        int t0 = g * 1024 + tid * 4;
        // r[b, t0..t0+3, :] = 8 consecutive floats = 2 float4 loads (coalesced)
        float4 p0 = *(const float4*)(rb + (size_t)t0 * 2);
        float4 p1 = *(const float4*)(rb + (size_t)t0 * 2 + 4);
        float tx[4] = {p0.x, p0.z, p1.x, p1.z};
        float ty[4] = {p0.y, p0.w, p1.y, p1.w};
#pragma unroll
        for (int k = 0; k < 4; ++k) {
            // ---- row A ----
            float dxA = fmaf(-ax, tx[k], ax);          // ax*(1-tx)
            float dyA = fmaf(-ay, ty[k], ay);
            float dA  = fmaf(dxA, dxA, dyA * dyA);
            float cA  = (dA > 0.0f) ? dxA * __builtin_amdgcn_rsqf(dA) : 1.0f;
            float eA  = 0.5f * __expf(-dA);            // 0.5*exp(-d)
            float fbA = fmaf(cA, eA, eA);              // 0.5*(1+c)*exp(-d)
            float vA  = (dA <= threshold) ? fbA : 0.0f;
            va[g * 4 + k] = vA;
            sumA += vA;
            // ---- row B (shares tx,ty) ----
            float dxB = fmaf(-bx, tx[k], bx);
            float dyB = fmaf(-by, ty[k], by);
            float dB  = fmaf(dxB, dxB, dyB * dyB);
            float cB  = (dB > 0.0f) ? dxB * __builtin_amdgcn_rsqf(dB) : 1.0f;
            float eB  = 0.5f * __expf(-dB);
            float fbB = fmaf(cB, eB, eB);
            float vB  = (dB <= threshold) ? fbB : 0.0f;
            vb[g * 4 + k] = vB;
            sumB += vB;
        }
    }

    // block-level row-sum reductions: wave64 shuffle, then LDS across 4 waves
#pragma unroll
    for (int off = 32; off > 0; off >>= 1) {
        sumA += __shfl_down(sumA, off, 64);
        sumB += __shfl_down(sumB, off, 64);
    }
    __shared__ float wsum[2][4];
    int lane = tid & 63;
    int wid = tid >> 6;
    if (lane == 0) { wsum[0][wid] = sumA; wsum[1][wid] = sumB; }
    __syncthreads();
    float totA = wsum[0][0] + wsum[0][1] + wsum[0][2] + wsum[0][3];
    float totB = wsum[1][0] + wsum[1][1] + wsum[1][2] + wsum[1][3];
    float invA = __builtin_amdgcn_rcpf(totA + 1e-8f);
    float invB = __builtin_amdgcn_rcpf(totB + 1e-8f);

    size_t rowA = ((size_t)b * N + (size_t)s0) * N;
    float4* outA = (float4*)(out + rowA);
    float4* outB = (float4*)(out + rowA + N);
#pragma unroll
    for (int g = 0; g < 4; ++g) {
        int t0 = g * 1024 + tid * 4;
        float4 w4;
        w4.x = va[g * 4 + 0] * invA;
        w4.y = va[g * 4 + 1] * invA;
        w4.z = va[g * 4 + 2] * invA;
        w4.w = va[g * 4 + 3] * invA;
        outA[t0 >> 2] = w4;
        float4 u4;
        u4.x = vb[g * 4 + 0] * invB;
        u4.y = vb[g * 4 + 1] * invB;
        u4.z = vb[g * 4 + 2] * invB;
        u4.w = vb[g * 4 + 3] * invB;
        outB[t0 >> 2] = u4;
    }
}

extern "C" void kernel_launch(void* const* d_in, const int* in_sizes, int n_in,
                              void* d_out, int out_size, void* d_ws, size_t ws_size,
                              hipStream_t stream) {
    const float* r = (const float*)d_in[0];
    float* out = (float*)d_out;
    float* thr = (float*)d_ws;  // 2 floats

    stats_kernel<<<NB, 256, 0, stream>>>(r, thr);
    attn_kernel<<<NB * 2048, 256, 0, stream>>>(r, thr, out);
}